// Round 7
// baseline (602.360 us; speedup 1.0000x reference)
//
#include <hip/hip_runtime.h>
#include <math.h>

#define Sn 100
#define Bn 128
#define NWc 430500
#define EWc 431080   // NW + NB

typedef __attribute__((ext_vector_type(8)))  short bhalf8;
typedef __attribute__((ext_vector_type(16))) float fx16;

__device__ __forceinline__ float sp_f(float r){
    return fmaxf(r, 0.f) + log1pf(__expf(-fabsf(r)));   // stable softplus
}
__device__ __forceinline__ ushort bfr(float f){          // fp32 -> bf16 RNE
    union { float f; uint u; } c; c.f = f;
    uint r = (c.u + 0x7FFFu + ((c.u >> 16) & 1u)) >> 16;
    return (ushort)r;
}

// ---------------- K00: softplus(rho) once for ALL params (shared across s) ----------------
__global__ void k00_sp(const float* __restrict__ rho_w, const float* __restrict__ rho_b,
                       float* __restrict__ sp_all){
    int i = blockIdx.x * blockDim.x + threadIdx.x;
    if (i < NWc)      sp_all[i] = sp_f(rho_w[i]);
    else if (i < EWc) sp_all[i] = sp_f(rho_b[i - NWc]);
}

// ---------------- K0a: w3 bf16 [s][kt25][o500][k32], fully coalesced both sides -----------
// block (kt, s); lane: orow=tid>>3, piece=tid&7 -> 128-B contiguous read runs, linear writes
__global__ __launch_bounds__(256) void k0_w3(const float* __restrict__ e,
        const float* __restrict__ mu_w, const float* __restrict__ sp_all,
        ushort* __restrict__ w3){
    int kt = blockIdx.x;      // 0..24
    int s  = blockIdx.y;      // 0..99
    int tid = threadIdx.x;
    int orow0 = tid >> 3;     // 0..31
    int piece = tid & 7;      // 0..7, 4 floats each
    const float* eb = e + (size_t)s*EWc + 25500 + kt*32 + piece*4;
    const float* mb = mu_w  + 25500 + kt*32 + piece*4;
    const float* pb = sp_all + 25500 + kt*32 + piece*4;
    ushort* wb = w3 + (size_t)s*400000 + kt*16000 + piece*4;
    #pragma unroll 4
    for (int o = orow0; o < 500; o += 32){
        float4 ev = *(const float4*)(eb + (size_t)o*800);
        float4 mv = *(const float4*)(mb + (size_t)o*800);
        float4 sv = *(const float4*)(pb + (size_t)o*800);
        ushort4 t;
        t.x = bfr(fmaf(sv.x, ev.x, mv.x));
        t.y = bfr(fmaf(sv.y, ev.y, mv.y));
        t.z = bfr(fmaf(sv.z, ev.z, mv.z));
        t.w = bfr(fmaf(sv.w, ev.w, mv.w));
        *(ushort4*)(wb + o*32) = t;
    }
}

// ---------------- K0b: small params (w1, w2r, w4, ball) ----------------
// w1 fp32 [s][500], w2r bf16 [s][kk25][oc64][ic32] (zero-padded via memset),
// w4 fp32 [s][5000], ball fp32 [s][580]
__global__ void k0_small(const float* __restrict__ e, const float* __restrict__ mu_w,
                       const float* __restrict__ sp_all, const float* __restrict__ mu_b,
                       float* __restrict__ w1, ushort* __restrict__ w2r,
                       float* __restrict__ w4, float* __restrict__ ball){
    const int per = 31080;  // 500 + 25000 + 5000 + 580
    int idx = blockIdx.x * blockDim.x + threadIdx.x;
    if (idx >= Sn * per) return;
    int s = idx / per, j = idx % per;
    if (j < 500){
        float v = fmaf(sp_all[j], e[(size_t)s*EWc + j], mu_w[j]);
        w1[s*500 + j] = v;
    } else if (j < 25500){
        int g = j;
        float v = fmaf(sp_all[g], e[(size_t)s*EWc + g], mu_w[g]);
        int j2 = j - 500;
        int oc = j2 / 500, rem = j2 % 500;
        int ic = rem / 25, kk = rem % 25;
        w2r[(size_t)s*51200 + (kk*64 + oc)*32 + ic] = bfr(v);
    } else if (j < 30500){
        int g = 425500 + (j - 25500);
        float v = fmaf(sp_all[g], e[(size_t)s*EWc + g], mu_w[g]);
        w4[s*5000 + (j - 25500)] = v;
    } else {
        int k = j - 30500;
        float v = fmaf(sp_all[NWc + k], e[(size_t)s*EWc + NWc + k], mu_b[k]);
        ball[s*580 + k] = v;
    }
}

// ---------------- K1: conv1 + ReLU + 2x2 maxpool ----------------
// h1p bf16 layout: [s][b][pix=y*12+x][ic20]  (channel-last for MFMA k2)
__global__ __launch_bounds__(256, 2) void k1_conv1(const float* __restrict__ x,
        const float* __restrict__ w1, const float* __restrict__ ball,
        ushort* __restrict__ h1p){
    __shared__ __align__(16) float xs[784];
    __shared__ __align__(16) float w1s[500];
    __shared__ float b1s[20];
    __shared__ __align__(16) ushort ots[2880];   // [pix144][ic20] bf16
    int bid = blockIdx.x;
    int s = bid / Bn, b = bid % Bn;
    int tid = threadIdx.x;
    for (int i = tid; i < 784; i += 256) xs[i] = x[b*784 + i];
    for (int i = tid; i < 500; i += 256) w1s[i] = w1[s*500 + i];
    if (tid < 20) b1s[tid] = ball[s*580 + tid];
    __syncthreads();
    if (tid < 240){
        int c = tid / 12, y = tid % 12;   // pooled row y, channel c

        float acc0[24], acc1[24];
        #pragma unroll
        for (int i = 0; i < 24; ++i){ acc0[i] = 0.f; acc1[i] = 0.f; }

        #pragma unroll
        for (int ky = 0; ky < 5; ++ky){
            float rlo[28], rhi[28];
            const float* plo = &xs[(2*y + ky) * 28];
            const float* phi = &xs[(2*y + ky + 1) * 28];
            #pragma unroll
            for (int cc = 0; cc < 28; cc += 4){
                float4 v0 = *(const float4*)(plo + cc);
                rlo[cc] = v0.x; rlo[cc+1] = v0.y; rlo[cc+2] = v0.z; rlo[cc+3] = v0.w;
                float4 v1 = *(const float4*)(phi + cc);
                rhi[cc] = v1.x; rhi[cc+1] = v1.y; rhi[cc+2] = v1.z; rhi[cc+3] = v1.w;
            }
            #pragma unroll
            for (int kx = 0; kx < 5; ++kx){
                float wv = w1s[c*25 + ky*5 + kx];
                #pragma unroll
                for (int cx = 0; cx < 24; ++cx){
                    acc0[cx] = fmaf(rlo[cx + kx], wv, acc0[cx]);
                    acc1[cx] = fmaf(rhi[cx + kx], wv, acc1[cx]);
                }
            }
        }
        float bias = b1s[c];
        #pragma unroll
        for (int px = 0; px < 12; ++px){
            float m = fmaxf(fmaxf(acc0[2*px], acc0[2*px+1]),
                            fmaxf(acc1[2*px], acc1[2*px+1]));
            ots[(y*12 + px)*20 + c] = bfr(fmaxf(m + bias, 0.f));
        }
    }
    __syncthreads();
    const uint* o32 = (const uint*)ots;
    uint* g32 = (uint*)(h1p + (s*Bn + b)*2880);
    for (int j = tid; j < 1440; j += 256) g32[j] = o32[j];
}

// ---------------- K2: conv2 + ReLU + pool via MFMA, B-frags direct from global (L2) ----------
// 25 per-(ky,kx) GEMMs over ic (K=20 pad 32); wave = one image (M=64 pix, N=64 oc)
// h2p bf16 layout [s][kt25][b128][k32] where flat feature i = kt*32 + k (i = oc*16+py*4+px)
#define ICS 40   // u16 stride per row in LDS (bank-stagger pad)
__global__ __launch_bounds__(256, 3) void k2_direct(const ushort* __restrict__ h1p,
        const ushort* __restrict__ w2r, const float* __restrict__ ball,
        ushort* __restrict__ h2p){
    __shared__ __align__(16) ushort img[4*144*ICS];   // 46080 B
    int bid = blockIdx.x;
    int s = bid >> 5, g = bid & 31;
    int tid = threadIdx.x;
    // stage 4 images: global [im][pix][20] -> LDS [im][pix][ICS] (cols 0..19)
    const uint* g32 = (const uint*)(h1p + (size_t)(s*Bn + g*4)*2880);
    uint* l32 = (uint*)img;
    for (int j = tid; j < 5760; j += 256){            // 4*1440 u32
        int im = j / 1440, r = j - im*1440;
        int p = r / 10, u = r - p*10;
        l32[im*2880 + p*20 + u] = g32[j];
    }
    for (int j = tid; j < 3456; j += 256){            // zero pad ic 20..31
        int im = j / 864, r = j - im*864;
        int p = r / 6, u = 10 + (r - p*6);
        l32[im*2880 + p*20 + u] = 0u;
    }
    __syncthreads();                                   // the ONLY barrier

    int wv = tid >> 6, l = tid & 63;
    int l31 = l & 31, q = l >> 5;
    const ushort* imgw = img + wv*5760;
    int pixb0 = ((l31      ) >> 3)*12 + (l31 & 7);    // m-tile 0 pixel base
    int pixb1 = ((l31 + 32 ) >> 3)*12 + (l31 & 7);    // m-tile 1
    const ushort* wb0 = w2r + (size_t)(s*25)*2048 + (l31     )*32;
    const ushort* wb1 = w2r + (size_t)(s*25)*2048 + (l31 + 32)*32;
    fx16 acc00 = (fx16)0.f, acc01 = (fx16)0.f, acc10 = (fx16)0.f, acc11 = (fx16)0.f;

    #pragma unroll 1
    for (int kk = 0; kk < 25; ++kk){
        int ky = kk / 5, kx = kk - ky*5;
        int poff = ky*12 + kx;
        #pragma unroll
        for (int ics = 0; ics < 2; ++ics){
            bhalf8 a0 = *(const bhalf8*)(imgw + (pixb0 + poff)*ICS + ics*16 + q*8);
            bhalf8 a1 = *(const bhalf8*)(imgw + (pixb1 + poff)*ICS + ics*16 + q*8);
            bhalf8 b0 = *(const bhalf8*)(wb0 + kk*2048 + ics*16 + q*8);
            bhalf8 b1 = *(const bhalf8*)(wb1 + kk*2048 + ics*16 + q*8);
            acc00 = __builtin_amdgcn_mfma_f32_32x32x16_bf16(a0, b0, acc00, 0, 0, 0);
            acc01 = __builtin_amdgcn_mfma_f32_32x32x16_bf16(a0, b1, acc01, 0, 0, 0);
            acc10 = __builtin_amdgcn_mfma_f32_32x32x16_bf16(a1, b0, acc10, 0, 0, 0);
            acc11 = __builtin_amdgcn_mfma_f32_32x32x16_bf16(a1, b1, acc11, 0, 0, 0);
        }
    }
    // epilogue: intra-lane 2x2 maxpool, bias+relu, bf16 store in [kt][b][k32] layout
    int b = g*4 + wv;
    ushort* dst = h2p + (size_t)s*102400 + (size_t)b*32;
    #pragma unroll
    for (int nt = 0; nt < 2; ++nt){
        int oc = nt*32 + l31;
        if (oc >= 50) continue;
        float bias = ball[s*580 + 20 + oc];
        #pragma unroll
        for (int mt = 0; mt < 2; ++mt){
            fx16 a;
            if (nt == 0) a = mt ? acc10 : acc00;
            else         a = mt ? acc11 : acc01;
            #pragma unroll
            for (int gp = 0; gp < 2; ++gp){
                float p0 = fmaxf(fmaxf(a[8*gp+0], a[8*gp+1]), fmaxf(a[8*gp+4], a[8*gp+5]));
                float p1 = fmaxf(fmaxf(a[8*gp+2], a[8*gp+3]), fmaxf(a[8*gp+6], a[8*gp+7]));
                p0 = fmaxf(p0 + bias, 0.f);
                p1 = fmaxf(p1 + bias, 0.f);
                int py = mt*2 + gp;
                int i  = oc*16 + py*4 + 2*q;          // flat feature index
                uint pk = (uint)bfr(p0) | ((uint)bfr(p1) << 16);
                *(uint*)(dst + (i >> 5)*4096 + (i & 31)) = pk;
            }
        }
    }
}

// ---------------- K3: aff1 via MFMA (per s: 128 x 512pad x 800), fully linear tiles --------
// A = h2p [s][kt][b128][k32], B = w3 [s][kt][o500][k32]; register-prefetched LDS staging.
// h3 fp32 [s][b][o500]
__global__ __launch_bounds__(256) void k3_mfma(const ushort* __restrict__ h2p,
        const ushort* __restrict__ w3, const float* __restrict__ ball,
        float* __restrict__ h3){
    __shared__ __align__(16) ushort As[128*ICS];   // 10240 B
    __shared__ __align__(16) ushort Bsh[64*ICS];   //  5120 B
    int bid = blockIdx.x;
    int s = bid >> 3, nblk = bid & 7;
    int o0 = nblk * 64;
    int tid = threadIdx.x;
    int wv = tid >> 6, l = tid & 63, l31 = l & 31, q = l >> 5;
    int wm = wv >> 1, wn = wv & 1;
    fx16 acc0 = (fx16)0.f, acc1 = (fx16)0.f;
    int rr = tid >> 2, rk = (tid & 3)*8;      // staging: row (0..63), k-offset
    const ushort* Abase = h2p + (size_t)s*102400;
    const ushort* Bbase = w3  + (size_t)s*400000 + (size_t)o0*32;
    bool bvalid = (o0 + rr) < 500;
    const uint4 z4 = make_uint4(0u,0u,0u,0u);

    uint4 ar0, ar1, br;                       // prefetch kt=0
    ar0 = *(const uint4*)(Abase + rr*32 + rk);
    ar1 = *(const uint4*)(Abase + (rr + 64)*32 + rk);
    br  = bvalid ? *(const uint4*)(Bbase + rr*32 + rk) : z4;

    for (int kt = 0; kt < 25; ++kt){
        __syncthreads();
        *(uint4*)&As[rr*ICS + rk]        = ar0;
        *(uint4*)&As[(rr + 64)*ICS + rk] = ar1;
        *(uint4*)&Bsh[rr*ICS + rk]       = br;
        __syncthreads();
        if (kt < 24){                         // prefetch next contiguous chunks
            ar0 = *(const uint4*)(Abase + (kt+1)*4096 + rr*32 + rk);
            ar1 = *(const uint4*)(Abase + (kt+1)*4096 + (rr + 64)*32 + rk);
            br  = bvalid ? *(const uint4*)(Bbase + (kt+1)*16000 + rr*32 + rk) : z4;
        }
        #pragma unroll
        for (int ks = 0; ks < 2; ++ks){
            bhalf8 a0 = *(const bhalf8*)&As[(wm*64      + l31)*ICS + ks*16 + q*8];
            bhalf8 a1 = *(const bhalf8*)&As[(wm*64 + 32 + l31)*ICS + ks*16 + q*8];
            bhalf8 bb = *(const bhalf8*)&Bsh[(wn*32 + l31)*ICS + ks*16 + q*8];
            acc0 = __builtin_amdgcn_mfma_f32_32x32x16_bf16(a0, bb, acc0, 0, 0, 0);
            acc1 = __builtin_amdgcn_mfma_f32_32x32x16_bf16(a1, bb, acc1, 0, 0, 0);
        }
    }
    int o = o0 + wn*32 + l31;
    if (o < 500){
        float bias = ball[s*580 + 70 + o];
        #pragma unroll
        for (int mt = 0; mt < 2; ++mt){
            fx16 a = mt ? acc1 : acc0;
            #pragma unroll
            for (int reg = 0; reg < 16; ++reg){
                int row = (reg & 3) + 8*(reg >> 2) + 4*q;
                int b = wm*64 + mt*32 + row;
                h3[(size_t)(s*Bn + b)*500 + o] = fmaxf(a[reg] + bias, 0.f);
            }
        }
    }
}

// ---------------- K4a: aff2 + log_softmax per (s,b) ----------------
__global__ __launch_bounds__(256) void k4a(const float* __restrict__ h3,
        const float* __restrict__ w4, const float* __restrict__ ball,
        float* __restrict__ lsw){
    int wv = threadIdx.x >> 6, lane = threadIdx.x & 63;
    int p = blockIdx.x*4 + wv;
    int s = p / Bn;
    const float* hp = &h3[(size_t)p*500];
    const float* wp = &w4[(size_t)s*5000];
    float part[10];
    #pragma unroll
    for (int o = 0; o < 10; ++o) part[o] = 0.f;
    for (int i = lane; i < 500; i += 64){
        float hv = hp[i];
        #pragma unroll
        for (int o = 0; o < 10; ++o)
            part[o] = fmaf(hv, wp[o*500 + i], part[o]);
    }
    #pragma unroll
    for (int o = 0; o < 10; ++o){
        #pragma unroll
        for (int d = 1; d < 64; d <<= 1)
            part[o] += __shfl_xor(part[o], d);
    }
    float v[10]; float m = -INFINITY;
    #pragma unroll
    for (int o = 0; o < 10; ++o){
        v[o] = part[o] + ball[s*580 + 570 + o];
        m = fmaxf(m, v[o]);
    }
    float sum = 0.f;
    #pragma unroll
    for (int o = 0; o < 10; ++o) sum += __expf(v[o] - m);
    float lse = m + __logf(sum);
    if (lane == 0){
        #pragma unroll
        for (int o = 0; o < 10; ++o) lsw[p*10 + o] = v[o] - lse;
    }
}

// ---------------- K4b: mean over samples ----------------
__global__ void k4b(const float* __restrict__ lsw, float* __restrict__ outp){
    int j = blockIdx.x * blockDim.x + threadIdx.x;
    if (j >= Bn*10) return;
    int b = j / 10, o = j % 10;
    float acc = 0.f;
    for (int s2 = 0; s2 < Sn; ++s2) acc += lsw[(s2*Bn + b)*10 + o];
    outp[j] = acc * (1.f / (float)Sn);
}

extern "C" void kernel_launch(void* const* d_in, const int* in_sizes, int n_in,
                              void* d_out, int out_size, void* d_ws, size_t ws_size,
                              hipStream_t stream){
    const float* x     = (const float*)d_in[0];
    const float* e     = (const float*)d_in[1];
    const float* mu_w  = (const float*)d_in[2];
    const float* rho_w = (const float*)d_in[3];
    const float* mu_b  = (const float*)d_in[4];
    const float* rho_b = (const float*)d_in[5];
    float* ws   = (float*)d_ws;
    float* w1     = ws;                       //     50,000 f
    float* w4     = w1 + 50000;               //    500,000 f
    float* ball   = w4 + 500000;              //     58,000 f
    float* h3     = ball + 58000;             //  6,400,000 f
    float* lsw    = h3 + 6400000;             //    128,000 f
    float* sp_all = lsw + 128000;             //    431,080 f
    ushort* h1p = (ushort*)(sp_all + 431080); // 36,864,000 u16
    ushort* h2p = h1p + 36864000;             // 10,240,000 u16
    ushort* w2r = h2p + 10240000;             //  5,120,000 u16
    ushort* w3  = w2r + 5120000;              // 40,000,000 u16 (80 MB)
    float* outp = (float*)d_out;

    hipMemsetAsync(w2r, 0, (size_t)Sn*51200*2, stream);
    k00_sp   <<<(EWc + 255)/256, 256, 0, stream>>>(rho_w, rho_b, sp_all);
    k0_w3    <<<dim3(25, Sn), 256, 0, stream>>>(e, mu_w, sp_all, w3);
    k0_small <<<(Sn*31080 + 255)/256, 256, 0, stream>>>(e, mu_w, sp_all, mu_b, w1, w2r, w4, ball);
    k1_conv1 <<<Sn*Bn, 256, 0, stream>>>(x, w1, ball, h1p);
    k2_direct<<<Sn*32, 256, 0, stream>>>(h1p, w2r, ball, h2p);
    k3_mfma  <<<Sn*8, 256, 0, stream>>>(h2p, w3, ball, h3);
    k4a      <<<3200, 256, 0, stream>>>(h3, w4, ball, lsw);
    k4b      <<<(Bn*10 + 255)/256, 256, 0, stream>>>(lsw, outp);
}

// Round 8
// 555.666 us; speedup vs baseline: 1.0840x; 1.0840x over previous
//
#include <hip/hip_runtime.h>
#include <math.h>

#define Sn 100
#define Bn 128
#define NWc 430500
#define EWc 431080   // NW + NB

typedef __attribute__((ext_vector_type(8)))  short bhalf8;
typedef __attribute__((ext_vector_type(16))) float fx16;

__device__ __forceinline__ float sp_f(float r){
    return fmaxf(r, 0.f) + log1pf(__expf(-fabsf(r)));   // stable softplus
}
__device__ __forceinline__ ushort bfr(float f){          // fp32 -> bf16 RNE
    union { float f; uint u; } c; c.f = f;
    uint r = (c.u + 0x7FFFu + ((c.u >> 16) & 1u)) >> 16;
    return (ushort)r;
}

// ---------------- K00: softplus(rho) once for ALL params (shared across s) ----------------
__global__ void k00_sp(const float* __restrict__ rho_w, const float* __restrict__ rho_b,
                       float* __restrict__ sp_all){
    int i = blockIdx.x * blockDim.x + threadIdx.x;
    if (i < NWc)      sp_all[i] = sp_f(rho_w[i]);
    else if (i < EWc) sp_all[i] = sp_f(rho_b[i - NWc]);
}

// ---------------- K0a: w3 bf16 [s][kt25][o500][k32] via LDS transpose ----------------
// block (o-chunk 20, s): Phase1 linear e/mu/sp read -> LDS [20][808];
// Phase2: per-kt 128-B contiguous writes. Both global sides fully streamed.
__global__ __launch_bounds__(256) void k0_w3t(const float* __restrict__ e,
        const float* __restrict__ mu_w, const float* __restrict__ sp_all,
        ushort* __restrict__ w3){
    __shared__ __align__(16) ushort ls[20*808];   // 32.3 KB
    int oc = blockIdx.x;      // 0..24  (o-chunk of 20 rows)
    int s  = blockIdx.y;      // 0..99
    int o0 = oc * 20;
    int tid = threadIdx.x;
    const float* eb = e + (size_t)s*EWc + 25500 + (size_t)o0*800;
    const float* mb = mu_w   + 25500 + (size_t)o0*800;
    const float* pb = sp_all + 25500 + (size_t)o0*800;
    #pragma unroll 4
    for (int j = tid; j < 4000; j += 256){        // 4000 float4 = 16000 floats
        int o = j / 200, k4 = j - o*200;
        float4 ev = *(const float4*)(eb + j*4);
        float4 mv = *(const float4*)(mb + j*4);
        float4 sv = *(const float4*)(pb + j*4);
        ushort4 t;
        t.x = bfr(fmaf(sv.x, ev.x, mv.x));
        t.y = bfr(fmaf(sv.y, ev.y, mv.y));
        t.z = bfr(fmaf(sv.z, ev.z, mv.z));
        t.w = bfr(fmaf(sv.w, ev.w, mv.w));
        *(ushort4*)&ls[o*808 + k4*4] = t;
    }
    __syncthreads();
    if (tid < 200){
        int kt = tid >> 3, l8 = tid & 7;          // 8 lanes per kt stripe
        ushort* wb = w3 + (size_t)s*400000 + kt*16000 + o0*32;
        #pragma unroll
        for (int it = 0; it < 10; ++it){
            int idx = it*8 + l8;                  // 0..79 uint4 per stripe
            int o = idx >> 2, kp = (idx & 3)*8;
            uint4 v = *(const uint4*)&ls[o*808 + kt*32 + kp];
            *(uint4*)(wb + idx*8) = v;            // 8 lanes -> 128 B contiguous
        }
    }
}

// ---------------- K0b: small params (w1, w2r, w4, ball) ----------------
// w1 fp32 [s][500], w2r bf16 [s][kk25][oc64][ic32] (zero-padded via memset),
// w4 fp32 [s][5000], ball fp32 [s][580]
__global__ void k0_small(const float* __restrict__ e, const float* __restrict__ mu_w,
                       const float* __restrict__ sp_all, const float* __restrict__ mu_b,
                       float* __restrict__ w1, ushort* __restrict__ w2r,
                       float* __restrict__ w4, float* __restrict__ ball){
    const int per = 31080;  // 500 + 25000 + 5000 + 580
    int idx = blockIdx.x * blockDim.x + threadIdx.x;
    if (idx >= Sn * per) return;
    int s = idx / per, j = idx % per;
    if (j < 500){
        float v = fmaf(sp_all[j], e[(size_t)s*EWc + j], mu_w[j]);
        w1[s*500 + j] = v;
    } else if (j < 25500){
        int g = j;
        float v = fmaf(sp_all[g], e[(size_t)s*EWc + g], mu_w[g]);
        int j2 = j - 500;
        int oc = j2 / 500, rem = j2 % 500;
        int ic = rem / 25, kk = rem % 25;
        w2r[(size_t)s*51200 + (kk*64 + oc)*32 + ic] = bfr(v);
    } else if (j < 30500){
        int g = 425500 + (j - 25500);
        float v = fmaf(sp_all[g], e[(size_t)s*EWc + g], mu_w[g]);
        w4[s*5000 + (j - 25500)] = v;
    } else {
        int k = j - 30500;
        float v = fmaf(sp_all[NWc + k], e[(size_t)s*EWc + NWc + k], mu_b[k]);
        ball[s*580 + k] = v;
    }
}

// ---------------- K1: conv1 + ReLU + 2x2 maxpool ----------------
// h1p bf16 layout: [s][b][pix=y*12+x][ic20]  (channel-last for MFMA k2)
__global__ __launch_bounds__(256, 2) void k1_conv1(const float* __restrict__ x,
        const float* __restrict__ w1, const float* __restrict__ ball,
        ushort* __restrict__ h1p){
    __shared__ __align__(16) float xs[784];
    __shared__ __align__(16) float w1s[500];
    __shared__ float b1s[20];
    __shared__ __align__(16) ushort ots[2880];   // [pix144][ic20] bf16
    int bid = blockIdx.x;
    int s = bid / Bn, b = bid % Bn;
    int tid = threadIdx.x;
    for (int i = tid; i < 784; i += 256) xs[i] = x[b*784 + i];
    for (int i = tid; i < 500; i += 256) w1s[i] = w1[s*500 + i];
    if (tid < 20) b1s[tid] = ball[s*580 + tid];
    __syncthreads();
    if (tid < 240){
        int c = tid / 12, y = tid % 12;   // pooled row y, channel c

        float acc0[24], acc1[24];
        #pragma unroll
        for (int i = 0; i < 24; ++i){ acc0[i] = 0.f; acc1[i] = 0.f; }

        #pragma unroll
        for (int ky = 0; ky < 5; ++ky){
            float rlo[28], rhi[28];
            const float* plo = &xs[(2*y + ky) * 28];
            const float* phi = &xs[(2*y + ky + 1) * 28];
            #pragma unroll
            for (int cc = 0; cc < 28; cc += 4){
                float4 v0 = *(const float4*)(plo + cc);
                rlo[cc] = v0.x; rlo[cc+1] = v0.y; rlo[cc+2] = v0.z; rlo[cc+3] = v0.w;
                float4 v1 = *(const float4*)(phi + cc);
                rhi[cc] = v1.x; rhi[cc+1] = v1.y; rhi[cc+2] = v1.z; rhi[cc+3] = v1.w;
            }
            #pragma unroll
            for (int kx = 0; kx < 5; ++kx){
                float wv = w1s[c*25 + ky*5 + kx];
                #pragma unroll
                for (int cx = 0; cx < 24; ++cx){
                    acc0[cx] = fmaf(rlo[cx + kx], wv, acc0[cx]);
                    acc1[cx] = fmaf(rhi[cx + kx], wv, acc1[cx]);
                }
            }
        }
        float bias = b1s[c];
        #pragma unroll
        for (int px = 0; px < 12; ++px){
            float m = fmaxf(fmaxf(acc0[2*px], acc0[2*px+1]),
                            fmaxf(acc1[2*px], acc1[2*px+1]));
            ots[(y*12 + px)*20 + c] = bfr(fmaxf(m + bias, 0.f));
        }
    }
    __syncthreads();
    const uint* o32 = (const uint*)ots;
    uint* g32 = (uint*)(h1p + (s*Bn + b)*2880);
    for (int j = tid; j < 1440; j += 256) g32[j] = o32[j];
}

// ---------------- K2: conv2 + ReLU + pool via MFMA, B-frags direct from global (L2) ----------
// 25 per-(ky,kx) GEMMs over ic (K=20 pad 32); wave = one image (M=64 pix, N=64 oc)
// h2p bf16 layout [s][kt25][b128][k32] where flat feature i = kt*32 + k (i = oc*16+py*4+px)
#define ICS 40   // u16 stride per row in LDS (bank-stagger pad)
__global__ __launch_bounds__(256, 3) void k2_direct(const ushort* __restrict__ h1p,
        const ushort* __restrict__ w2r, const float* __restrict__ ball,
        ushort* __restrict__ h2p){
    __shared__ __align__(16) ushort img[4*144*ICS];   // 46080 B
    int bid = blockIdx.x;
    int s = bid >> 5, g = bid & 31;
    int tid = threadIdx.x;
    // stage 4 images: global [im][pix][20] -> LDS [im][pix][ICS] (cols 0..19)
    const uint* g32 = (const uint*)(h1p + (size_t)(s*Bn + g*4)*2880);
    uint* l32 = (uint*)img;
    for (int j = tid; j < 5760; j += 256){            // 4*1440 u32
        int im = j / 1440, r = j - im*1440;
        int p = r / 10, u = r - p*10;
        l32[im*2880 + p*20 + u] = g32[j];
    }
    for (int j = tid; j < 3456; j += 256){            // zero pad ic 20..31
        int im = j / 864, r = j - im*864;
        int p = r / 6, u = 10 + (r - p*6);
        l32[im*2880 + p*20 + u] = 0u;
    }
    __syncthreads();                                   // the ONLY barrier

    int wv = tid >> 6, l = tid & 63;
    int l31 = l & 31, q = l >> 5;
    const ushort* imgw = img + wv*5760;
    int pixb0 = ((l31      ) >> 3)*12 + (l31 & 7);    // m-tile 0 pixel base
    int pixb1 = ((l31 + 32 ) >> 3)*12 + (l31 & 7);    // m-tile 1
    const ushort* wb0 = w2r + (size_t)(s*25)*2048 + (l31     )*32;
    const ushort* wb1 = w2r + (size_t)(s*25)*2048 + (l31 + 32)*32;
    fx16 acc00 = (fx16)0.f, acc01 = (fx16)0.f, acc10 = (fx16)0.f, acc11 = (fx16)0.f;

    #pragma unroll 1
    for (int kk = 0; kk < 25; ++kk){
        int ky = kk / 5, kx = kk - ky*5;
        int poff = ky*12 + kx;
        #pragma unroll
        for (int ics = 0; ics < 2; ++ics){
            bhalf8 a0 = *(const bhalf8*)(imgw + (pixb0 + poff)*ICS + ics*16 + q*8);
            bhalf8 a1 = *(const bhalf8*)(imgw + (pixb1 + poff)*ICS + ics*16 + q*8);
            bhalf8 b0 = *(const bhalf8*)(wb0 + kk*2048 + ics*16 + q*8);
            bhalf8 b1 = *(const bhalf8*)(wb1 + kk*2048 + ics*16 + q*8);
            acc00 = __builtin_amdgcn_mfma_f32_32x32x16_bf16(a0, b0, acc00, 0, 0, 0);
            acc01 = __builtin_amdgcn_mfma_f32_32x32x16_bf16(a0, b1, acc01, 0, 0, 0);
            acc10 = __builtin_amdgcn_mfma_f32_32x32x16_bf16(a1, b0, acc10, 0, 0, 0);
            acc11 = __builtin_amdgcn_mfma_f32_32x32x16_bf16(a1, b1, acc11, 0, 0, 0);
        }
    }
    // epilogue: intra-lane 2x2 maxpool, bias+relu, bf16 store in [kt][b][k32] layout
    int b = g*4 + wv;
    ushort* dst = h2p + (size_t)s*102400 + (size_t)b*32;
    #pragma unroll
    for (int nt = 0; nt < 2; ++nt){
        int oc = nt*32 + l31;
        if (oc >= 50) continue;
        float bias = ball[s*580 + 20 + oc];
        #pragma unroll
        for (int mt = 0; mt < 2; ++mt){
            fx16 a;
            if (nt == 0) a = mt ? acc10 : acc00;
            else         a = mt ? acc11 : acc01;
            #pragma unroll
            for (int gp = 0; gp < 2; ++gp){
                float p0 = fmaxf(fmaxf(a[8*gp+0], a[8*gp+1]), fmaxf(a[8*gp+4], a[8*gp+5]));
                float p1 = fmaxf(fmaxf(a[8*gp+2], a[8*gp+3]), fmaxf(a[8*gp+6], a[8*gp+7]));
                p0 = fmaxf(p0 + bias, 0.f);
                p1 = fmaxf(p1 + bias, 0.f);
                int py = mt*2 + gp;
                int i  = oc*16 + py*4 + 2*q;          // flat feature index
                uint pk = (uint)bfr(p0) | ((uint)bfr(p1) << 16);
                *(uint*)(dst + (i >> 5)*4096 + (i & 31)) = pk;
            }
        }
    }
}

// ---------------- K3: aff1 via MFMA (per s: 128 x 512pad x 800), fully linear tiles --------
// A = h2p [s][kt][b128][k32], B = w3 [s][kt][o500][k32]; register-prefetched LDS staging.
// h3 fp32 [s][b][o500]
__global__ __launch_bounds__(256) void k3_mfma(const ushort* __restrict__ h2p,
        const ushort* __restrict__ w3, const float* __restrict__ ball,
        float* __restrict__ h3){
    __shared__ __align__(16) ushort As[128*ICS];   // 10240 B
    __shared__ __align__(16) ushort Bsh[64*ICS];   //  5120 B
    int bid = blockIdx.x;
    int s = bid >> 3, nblk = bid & 7;
    int o0 = nblk * 64;
    int tid = threadIdx.x;
    int wv = tid >> 6, l = tid & 63, l31 = l & 31, q = l >> 5;
    int wm = wv >> 1, wn = wv & 1;
    fx16 acc0 = (fx16)0.f, acc1 = (fx16)0.f;
    int rr = tid >> 2, rk = (tid & 3)*8;      // staging: row (0..63), k-offset
    const ushort* Abase = h2p + (size_t)s*102400;
    const ushort* Bbase = w3  + (size_t)s*400000 + (size_t)o0*32;
    bool bvalid = (o0 + rr) < 500;
    const uint4 z4 = make_uint4(0u,0u,0u,0u);

    uint4 ar0, ar1, br;                       // prefetch kt=0
    ar0 = *(const uint4*)(Abase + rr*32 + rk);
    ar1 = *(const uint4*)(Abase + (rr + 64)*32 + rk);
    br  = bvalid ? *(const uint4*)(Bbase + rr*32 + rk) : z4;

    for (int kt = 0; kt < 25; ++kt){
        __syncthreads();
        *(uint4*)&As[rr*ICS + rk]        = ar0;
        *(uint4*)&As[(rr + 64)*ICS + rk] = ar1;
        *(uint4*)&Bsh[rr*ICS + rk]       = br;
        __syncthreads();
        if (kt < 24){                         // prefetch next contiguous chunks
            ar0 = *(const uint4*)(Abase + (kt+1)*4096 + rr*32 + rk);
            ar1 = *(const uint4*)(Abase + (kt+1)*4096 + (rr + 64)*32 + rk);
            br  = bvalid ? *(const uint4*)(Bbase + (kt+1)*16000 + rr*32 + rk) : z4;
        }
        #pragma unroll
        for (int ks = 0; ks < 2; ++ks){
            bhalf8 a0 = *(const bhalf8*)&As[(wm*64      + l31)*ICS + ks*16 + q*8];
            bhalf8 a1 = *(const bhalf8*)&As[(wm*64 + 32 + l31)*ICS + ks*16 + q*8];
            bhalf8 bb = *(const bhalf8*)&Bsh[(wn*32 + l31)*ICS + ks*16 + q*8];
            acc0 = __builtin_amdgcn_mfma_f32_32x32x16_bf16(a0, bb, acc0, 0, 0, 0);
            acc1 = __builtin_amdgcn_mfma_f32_32x32x16_bf16(a1, bb, acc1, 0, 0, 0);
        }
    }
    int o = o0 + wn*32 + l31;
    if (o < 500){
        float bias = ball[s*580 + 70 + o];
        #pragma unroll
        for (int mt = 0; mt < 2; ++mt){
            fx16 a = mt ? acc1 : acc0;
            #pragma unroll
            for (int reg = 0; reg < 16; ++reg){
                int row = (reg & 3) + 8*(reg >> 2) + 4*q;
                int b = wm*64 + mt*32 + row;
                h3[(size_t)(s*Bn + b)*500 + o] = fmaxf(a[reg] + bias, 0.f);
            }
        }
    }
}

// ---------------- K4a: aff2 + log_softmax per (s,b) ----------------
__global__ __launch_bounds__(256) void k4a(const float* __restrict__ h3,
        const float* __restrict__ w4, const float* __restrict__ ball,
        float* __restrict__ lsw){
    int wv = threadIdx.x >> 6, lane = threadIdx.x & 63;
    int p = blockIdx.x*4 + wv;
    int s = p / Bn;
    const float* hp = &h3[(size_t)p*500];
    const float* wp = &w4[(size_t)s*5000];
    float part[10];
    #pragma unroll
    for (int o = 0; o < 10; ++o) part[o] = 0.f;
    for (int i = lane; i < 500; i += 64){
        float hv = hp[i];
        #pragma unroll
        for (int o = 0; o < 10; ++o)
            part[o] = fmaf(hv, wp[o*500 + i], part[o]);
    }
    #pragma unroll
    for (int o = 0; o < 10; ++o){
        #pragma unroll
        for (int d = 1; d < 64; d <<= 1)
            part[o] += __shfl_xor(part[o], d);
    }
    float v[10]; float m = -INFINITY;
    #pragma unroll
    for (int o = 0; o < 10; ++o){
        v[o] = part[o] + ball[s*580 + 570 + o];
        m = fmaxf(m, v[o]);
    }
    float sum = 0.f;
    #pragma unroll
    for (int o = 0; o < 10; ++o) sum += __expf(v[o] - m);
    float lse = m + __logf(sum);
    if (lane == 0){
        #pragma unroll
        for (int o = 0; o < 10; ++o) lsw[p*10 + o] = v[o] - lse;
    }
}

// ---------------- K4b: mean over samples ----------------
__global__ void k4b(const float* __restrict__ lsw, float* __restrict__ outp){
    int j = blockIdx.x * blockDim.x + threadIdx.x;
    if (j >= Bn*10) return;
    int b = j / 10, o = j % 10;
    float acc = 0.f;
    for (int s2 = 0; s2 < Sn; ++s2) acc += lsw[(s2*Bn + b)*10 + o];
    outp[j] = acc * (1.f / (float)Sn);
}

extern "C" void kernel_launch(void* const* d_in, const int* in_sizes, int n_in,
                              void* d_out, int out_size, void* d_ws, size_t ws_size,
                              hipStream_t stream){
    const float* x     = (const float*)d_in[0];
    const float* e     = (const float*)d_in[1];
    const float* mu_w  = (const float*)d_in[2];
    const float* rho_w = (const float*)d_in[3];
    const float* mu_b  = (const float*)d_in[4];
    const float* rho_b = (const float*)d_in[5];
    float* ws   = (float*)d_ws;
    float* w1     = ws;                       //     50,000 f
    float* w4     = w1 + 50000;               //    500,000 f
    float* ball   = w4 + 500000;              //     58,000 f
    float* h3     = ball + 58000;             //  6,400,000 f
    float* lsw    = h3 + 6400000;             //    128,000 f
    float* sp_all = lsw + 128000;             //    431,080 f
    ushort* h1p = (ushort*)(sp_all + 431080); // 36,864,000 u16
    ushort* h2p = h1p + 36864000;             // 10,240,000 u16
    ushort* w2r = h2p + 10240000;             //  5,120,000 u16
    ushort* w3  = w2r + 5120000;              // 40,000,000 u16 (80 MB)
    float* outp = (float*)d_out;

    hipMemsetAsync(w2r, 0, (size_t)Sn*51200*2, stream);
    k00_sp   <<<(EWc + 255)/256, 256, 0, stream>>>(rho_w, rho_b, sp_all);
    k0_w3t   <<<dim3(25, Sn), 256, 0, stream>>>(e, mu_w, sp_all, w3);
    k0_small <<<(Sn*31080 + 255)/256, 256, 0, stream>>>(e, mu_w, sp_all, mu_b, w1, w2r, w4, ball);
    k1_conv1 <<<Sn*Bn, 256, 0, stream>>>(x, w1, ball, h1p);
    k2_direct<<<Sn*32, 256, 0, stream>>>(h1p, w2r, ball, h2p);
    k3_mfma  <<<Sn*8, 256, 0, stream>>>(h2p, w3, ball, h3);
    k4a      <<<3200, 256, 0, stream>>>(h3, w4, ball, lsw);
    k4b      <<<(Bn*10 + 255)/256, 256, 0, stream>>>(lsw, outp);
}